// Round 11
// baseline (375.028 us; speedup 1.0000x reference)
//
#include <hip/hip_runtime.h>
#include <hip/hip_bf16.h>

typedef __attribute__((ext_vector_type(8))) short short8;
typedef __attribute__((ext_vector_type(4))) float floatx4;

#define NRES 700
#define DDIM 1024
#define HID 1024
// M = 89600 = 350*256, K = 1024, N = 1024 = 4*256.
// Main GEMM: BM=BN=256, BK=64, 16 K-tiles, 2 LDS buffers (128 KB), 4 phases/tile.

__device__ __forceinline__ unsigned short f2bf(float f) {
  unsigned u = __float_as_uint(f);
  u = (u + 0x7FFFu + ((u >> 16) & 1u)) >> 16;  // RNE
  return (unsigned short)u;
}

__device__ __forceinline__ void async_copy16(void* lds, const void* g) {
  __builtin_amdgcn_global_load_lds(
      (const __attribute__((address_space(1))) unsigned*)g,
      (__attribute__((address_space(3))) unsigned*)lds, 16, 0, 0);
}

// ---- prepass: A fp32 -> bf16 (streaming, memory-bound, ~83 us = BW floor) ----
__global__ void convert_a_kernel(const float* __restrict__ A,
                                 unsigned short* __restrict__ Abf, long n8) {
  long i = (long)blockIdx.x * blockDim.x + threadIdx.x;
  long stride = (long)gridDim.x * blockDim.x;
  for (; i < n8; i += stride) {
    const float* p = A + i * 8;
    float4 f0 = *(const float4*)p;
    float4 f1 = *(const float4*)(p + 4);
    int4 pk;
    pk.x = f2bf(f0.x) | ((unsigned)f2bf(f0.y) << 16);
    pk.y = f2bf(f0.z) | ((unsigned)f2bf(f0.w) << 16);
    pk.z = f2bf(f1.x) | ((unsigned)f2bf(f1.y) << 16);
    pk.w = f2bf(f1.z) | ((unsigned)f2bf(f1.w) << 16);
    *(int4*)(Abf + i * 8) = pk;
  }
}

// W1 [d][h] fp32 -> W1T [h][d] bf16
__global__ void transpose_w1_kernel(const float* __restrict__ W1,
                                    unsigned short* __restrict__ W1T) {
  __shared__ float tile[32][33];
  int bx = blockIdx.x, by = blockIdx.y;
  int tx = threadIdx.x, ty = threadIdx.y;
#pragma unroll
  for (int i = 0; i < 32; i += 8)
    tile[ty + i][tx] = W1[(size_t)(by * 32 + ty + i) * HID + bx * 32 + tx];
  __syncthreads();
#pragma unroll
  for (int i = 0; i < 32; i += 8)
    W1T[(size_t)(bx * 32 + ty + i) * DDIM + by * 32 + tx] = f2bf(tile[tx][ty + i]);
}

__global__ void init_out_kernel(float* __restrict__ out, const float* __restrict__ b2, int n) {
  int i = blockIdx.x * blockDim.x + threadIdx.x;
  if (i < n) out[i] = b2[0];
}

// ---- main: 256x256 4-phase/tile deep pipeline (T2+T3+T4+T5), derived from
// the m201 template constants. Buffers: 2 x {A 32KB + B 32KB}. Per tile t:
//   ph1: read A-mq0(8) + B-all(8); stage (t+1)A1; bar; lgkm0; 16 MFMA (0,0)
//   ph2: stage (t+2)B0;                          bar;        16 MFMA (0,1)
//   ph3: read A-mq1(8); stage (t+2)B1;           bar; lgkm0; 16 MFMA (1,0)
//   ph4: stage (t+2)A0; bar; 16 MFMA (1,1); vmcnt(6); bar
// Region free-times: B0/B1 after ph1, A0/A1 after ph3 -> every overwrite is
// after its region's last-read barrier. vmcnt(6) at ph4 = t+1 fully landed,
// t+2's 3 staged halves stay in flight (never drains mid-loop).
// LDS swizzle: 128B rows, involution slot ^= (row&7) both sides (0-conflict).
__launch_bounds__(512, 2)
__global__ void gemm256_kernel(const unsigned short* __restrict__ Abf,
                               const unsigned short* __restrict__ W1T,
                               const float* __restrict__ b1,
                               const float* __restrict__ W2,
                               float* __restrict__ out) {
  __shared__ __align__(16) unsigned short As[2][256 * 64];  // 2 x 32 KB
  __shared__ __align__(16) unsigned short Bs[2][256 * 64];  // 2 x 32 KB

  int bid = blockIdx.x;
  // bijective XCD swizzle: 1400 = 8 * 175; 4 consecutive w share the A-panel
  int w = (bid & 7) * 175 + (bid >> 3);
  int blk_m = w >> 2;  // 0..349
  int blk_n = w & 3;   // 0..3
  int m0 = blk_m * 256;
  int n0 = blk_n * 256;

  int tid = threadIdx.x;            // 0..511
  int lane = tid & 63;
  int wid = tid >> 6;               // 0..7
  int wm = wid >> 2, wn = wid & 3;  // 2x4 wave grid; wave tile 128(M) x 64(N)
  int lrow = lane & 15, lk = lane >> 4;

  floatx4 acc[8][4];
#pragma unroll
  for (int i = 0; i < 8; ++i)
#pragma unroll
    for (int j = 0; j < 4; ++j) acc[i][j] = (floatx4)(0.f);

  // stage one half-tile (128 rows) of A or B for K-tile kt into buffer sb
  auto stageA = [&](int sb, int kt, int half) {
#pragma unroll
    for (int i = 0; i < 2; ++i) {
      int d = i * 512 + tid;          // chunk 0..1023 within the half
      int row = d >> 3, slot = d & 7;
      int sc = slot ^ (row & 7);      // inverse-swizzled source chunk
      async_copy16(&As[sb][half * 8192 + (d & ~63) * 8],
                   Abf + (size_t)(m0 + half * 128 + row) * DDIM + kt * 64 + sc * 8);
    }
  };
  auto stageB = [&](int sb, int kt, int half) {
#pragma unroll
    for (int i = 0; i < 2; ++i) {
      int d = i * 512 + tid;
      int row = d >> 3, slot = d & 7;
      int sc = slot ^ (row & 7);
      async_copy16(&Bs[sb][half * 8192 + (d & ~63) * 8],
                   W1T + (size_t)(n0 + half * 128 + row) * DDIM + kt * 64 + sc * 8);
    }
  };

  // ---- prologue: t0 all 4 halves, t1 first 3; vmcnt(6) -> t0 resident ----
  stageB(0, 0, 0); stageB(0, 0, 1); stageA(0, 0, 0); stageA(0, 0, 1);
  stageB(1, 1, 0); stageB(1, 1, 1); stageA(1, 1, 0);
  asm volatile("s_waitcnt vmcnt(6)" ::: "memory");
  __builtin_amdgcn_s_barrier();

  short8 af[2][4], bfv[2][4];

  for (int t = 0; t < 16; ++t) {
    const int buf = t & 1, nbuf = buf ^ 1;

    // ============ phase 1: A-mq0 + B-all reads; stage (t+1)A1 ============
#pragma unroll
    for (int ks = 0; ks < 2; ++ks) {
#pragma unroll
      for (int f = 0; f < 4; ++f) {
        int row = wm * 128 + f * 16 + lrow;  // mq0
        int slot = (ks * 4 + lk) ^ (row & 7);
        af[ks][f] = *(const short8*)&As[buf][row * 64 + slot * 8];
      }
#pragma unroll
      for (int g = 0; g < 4; ++g) {
        int row = wn * 64 + g * 16 + lrow;
        int slot = (ks * 4 + lk) ^ (row & 7);
        bfv[ks][g] = *(const short8*)&Bs[buf][row * 64 + slot * 8];
      }
    }
    if (t + 1 < 16) stageA(nbuf, t + 1, 1);
    __builtin_amdgcn_s_barrier();
    asm volatile("s_waitcnt lgkmcnt(0)" ::: "memory");
    __builtin_amdgcn_sched_barrier(0);
    __builtin_amdgcn_s_setprio(1);
#pragma unroll
    for (int ks = 0; ks < 2; ++ks)
#pragma unroll
      for (int f = 0; f < 4; ++f)
#pragma unroll
        for (int g = 0; g < 2; ++g)
          acc[f][g] = __builtin_amdgcn_mfma_f32_16x16x32_bf16(af[ks][f], bfv[ks][g], acc[f][g], 0, 0, 0);
    __builtin_amdgcn_s_setprio(0);
    __builtin_amdgcn_s_barrier();

    // ============ phase 2: stage (t+2)B0; MFMA (mq0,nq1) ============
    if (t + 2 < 16) stageB(buf, t + 2, 0);
    __builtin_amdgcn_s_barrier();
    __builtin_amdgcn_s_setprio(1);
#pragma unroll
    for (int ks = 0; ks < 2; ++ks)
#pragma unroll
      for (int f = 0; f < 4; ++f)
#pragma unroll
        for (int g = 0; g < 2; ++g)
          acc[f][2 + g] = __builtin_amdgcn_mfma_f32_16x16x32_bf16(af[ks][f], bfv[ks][2 + g], acc[f][2 + g], 0, 0, 0);
    __builtin_amdgcn_s_setprio(0);
    __builtin_amdgcn_s_barrier();

    // ============ phase 3: A-mq1 reads; stage (t+2)B1; MFMA (mq1,nq0) ====
#pragma unroll
    for (int ks = 0; ks < 2; ++ks)
#pragma unroll
      for (int f = 0; f < 4; ++f) {
        int row = wm * 128 + 64 + f * 16 + lrow;  // mq1
        int slot = (ks * 4 + lk) ^ (row & 7);
        af[ks][f] = *(const short8*)&As[buf][row * 64 + slot * 8];
      }
    if (t + 2 < 16) stageB(buf, t + 2, 1);
    __builtin_amdgcn_s_barrier();
    asm volatile("s_waitcnt lgkmcnt(0)" ::: "memory");
    __builtin_amdgcn_sched_barrier(0);
    __builtin_amdgcn_s_setprio(1);
#pragma unroll
    for (int ks = 0; ks < 2; ++ks)
#pragma unroll
      for (int f = 0; f < 4; ++f)
#pragma unroll
        for (int g = 0; g < 2; ++g)
          acc[4 + f][g] = __builtin_amdgcn_mfma_f32_16x16x32_bf16(af[ks][f], bfv[ks][g], acc[4 + f][g], 0, 0, 0);
    __builtin_amdgcn_s_setprio(0);
    __builtin_amdgcn_s_barrier();

    // ============ phase 4: stage (t+2)A0; MFMA (mq1,nq1); vmcnt ============
    if (t + 2 < 16) stageA(buf, t + 2, 0);
    __builtin_amdgcn_s_barrier();
    __builtin_amdgcn_s_setprio(1);
#pragma unroll
    for (int ks = 0; ks < 2; ++ks)
#pragma unroll
      for (int f = 0; f < 4; ++f)
#pragma unroll
        for (int g = 0; g < 2; ++g)
          acc[4 + f][2 + g] = __builtin_amdgcn_mfma_f32_16x16x32_bf16(af[ks][f], bfv[ks][2 + g], acc[4 + f][2 + g], 0, 0, 0);
    __builtin_amdgcn_s_setprio(0);
    if (t < 14)
      asm volatile("s_waitcnt vmcnt(6)" ::: "memory");  // t+1 landed; t+2 flies
    else if (t == 14)
      asm volatile("s_waitcnt vmcnt(0)" ::: "memory");  // tail drain
    if (t < 15) __builtin_amdgcn_s_barrier();
  }

  // ---- epilogue: +b1, relu, dot W2, shfl-reduce 16 cols, atomicAdd ----
  float w2v[4], b1v[4];
#pragma unroll
  for (int g = 0; g < 4; ++g) {
    int col = n0 + wn * 64 + g * 16 + lrow;
    w2v[g] = W2[col];
    b1v[g] = b1[col];
  }
#pragma unroll
  for (int mf = 0; mf < 8; ++mf) {
#pragma unroll
    for (int j = 0; j < 4; ++j) {
      float p = 0.f;
#pragma unroll
      for (int g = 0; g < 4; ++g) {
        float h = acc[mf][g][j] + b1v[g];
        h = fmaxf(h, 0.f);
        p += h * w2v[g];
      }
      p += __shfl_xor(p, 1);
      p += __shfl_xor(p, 2);
      p += __shfl_xor(p, 4);
      p += __shfl_xor(p, 8);
      if ((lane & 15) == 0) {
        int grow = m0 + wm * 128 + mf * 16 + (lk << 2) + j;    // global M = r*128+b
        atomicAdd(&out[(grow & 127) * NRES + (grow >> 7)], p); // out[b*700 + r]
      }
    }
  }
}

// ---- fallback (round-2 proven, reg-staged fp32 A): used if ws too small ----
__launch_bounds__(256, 2)
__global__ void fused_mlp_fallback(const float* __restrict__ A,
                                   const unsigned short* __restrict__ W1T,
                                   const float* __restrict__ b1,
                                   const float* __restrict__ W2,
                                   float* __restrict__ out) {
  __shared__ unsigned short As[128 * 64];
  __shared__ unsigned short Bs[128 * 64];
  int bid = blockIdx.x;
  int w = (bid & 7) * 700 + (bid >> 3);
  int blk_m = w >> 3, blk_n = w & 7;
  int m0 = blk_m * 128, n0 = blk_n * 128;
  int t = threadIdx.x, lane = t & 63, wid = t >> 6;
  int wm = wid >> 1, wn = wid & 1;
  int lrow = lane & 15, lk = lane >> 4;
  floatx4 acc[4][4];
#pragma unroll
  for (int i = 0; i < 4; ++i)
#pragma unroll
    for (int j = 0; j < 4; ++j) acc[i][j] = (floatx4)(0.f);
  for (int kt = 0; kt < 16; ++kt) {
    int k0 = kt * 64;
#pragma unroll
    for (int i = 0; i < 4; ++i) {
      int c = i * 256 + t;
      int row = c >> 3, c8 = c & 7;
      int dst = row * 64 + ((c8 ^ (row & 7)) * 8);
      const float* gp = A + (size_t)(m0 + row) * DDIM + k0 + c8 * 8;
      float4 f0 = *(const float4*)gp;
      float4 f1 = *(const float4*)(gp + 4);
      int4 pk;
      pk.x = f2bf(f0.x) | ((unsigned)f2bf(f0.y) << 16);
      pk.y = f2bf(f0.z) | ((unsigned)f2bf(f0.w) << 16);
      pk.z = f2bf(f1.x) | ((unsigned)f2bf(f1.y) << 16);
      pk.w = f2bf(f1.z) | ((unsigned)f2bf(f1.w) << 16);
      *(int4*)(&As[dst]) = pk;
      const unsigned short* gb = W1T + (size_t)(n0 + row) * DDIM + k0 + c8 * 8;
      *(int4*)(&Bs[dst]) = *(const int4*)gb;
    }
    __syncthreads();
#pragma unroll
    for (int ks = 0; ks < 2; ++ks) {
      short8 af[4], bf[4];
#pragma unroll
      for (int f = 0; f < 4; ++f) {
        int arow = wm * 64 + f * 16 + lrow;
        int ac = (ks * 4 + lk) ^ (arow & 7);
        af[f] = *(const short8*)(&As[arow * 64 + ac * 8]);
        int brow = wn * 64 + f * 16 + lrow;
        int bc = (ks * 4 + lk) ^ (brow & 7);
        bf[f] = *(const short8*)(&Bs[brow * 64 + bc * 8]);
      }
#pragma unroll
      for (int fm = 0; fm < 4; ++fm)
#pragma unroll
        for (int fn = 0; fn < 4; ++fn)
          acc[fm][fn] = __builtin_amdgcn_mfma_f32_16x16x32_bf16(af[fm], bf[fn], acc[fm][fn], 0, 0, 0);
    }
    __syncthreads();
  }
  float w2v[4], b1v[4];
#pragma unroll
  for (int fn = 0; fn < 4; ++fn) {
    int col = n0 + wn * 64 + fn * 16 + lrow;
    w2v[fn] = W2[col];
    b1v[fn] = b1[col];
  }
#pragma unroll
  for (int fm = 0; fm < 4; ++fm) {
#pragma unroll
    for (int j = 0; j < 4; ++j) {
      float p = 0.f;
#pragma unroll
      for (int fn = 0; fn < 4; ++fn) {
        float h = acc[fm][fn][j] + b1v[fn];
        h = fmaxf(h, 0.f);
        p += h * w2v[fn];
      }
      p += __shfl_xor(p, 1);
      p += __shfl_xor(p, 2);
      p += __shfl_xor(p, 4);
      p += __shfl_xor(p, 8);
      if ((lane & 15) == 0) {
        int row = wm * 64 + fm * 16 + (lk << 2) + j;
        atomicAdd(&out[row * NRES + blk_m], p);
      }
    }
  }
}

extern "C" void kernel_launch(void* const* d_in, const int* in_sizes, int n_in,
                              void* d_out, int out_size, void* d_ws, size_t ws_size,
                              hipStream_t stream) {
  const float* s_s = (const float*)d_in[0];  // [700,128,1024] fp32
  const float* W1 = (const float*)d_in[1];   // [1024,1024]
  const float* b1 = (const float*)d_in[2];   // [1024]
  const float* W2 = (const float*)d_in[3];   // [1024,1]
  const float* b2 = (const float*)d_in[4];   // [1]
  float* out = (float*)d_out;                // [128,700,1] fp32

  unsigned short* W1T = (unsigned short*)d_ws;  // 2 MB bf16
  const size_t w1t_bytes = (size_t)HID * DDIM * 2;
  const size_t abf_bytes = (size_t)NRES * 128 * DDIM * 2;  // 183.5 MB

  dim3 tb(32, 8);
  dim3 tg(HID / 32, DDIM / 32);
  transpose_w1_kernel<<<tg, tb, 0, stream>>>(W1, W1T);

  init_out_kernel<<<(out_size + 255) / 256, 256, 0, stream>>>(out, b2, out_size);

  if (ws_size >= w1t_bytes + abf_bytes) {
    unsigned short* Abf = (unsigned short*)((char*)d_ws + w1t_bytes);
    long n8 = (long)NRES * 128 * DDIM / 8;
    convert_a_kernel<<<2048, 256, 0, stream>>>(s_s, Abf, n8);
    gemm256_kernel<<<350 * 4, 512, 0, stream>>>(Abf, W1T, b1, W2, out);
  } else {
    fused_mlp_fallback<<<NRES * 8, 256, 0, stream>>>(s_s, W1T, b1, W2, out);
  }
}

// Round 12
// 302.568 us; speedup vs baseline: 1.2395x; 1.2395x over previous
//
#include <hip/hip_runtime.h>
#include <hip/hip_bf16.h>

typedef __attribute__((ext_vector_type(8))) short short8;
typedef __attribute__((ext_vector_type(4))) float floatx4;

#define NRES 700
#define DDIM 1024
#define HID 1024
// M = 89600, K = 1024, N = 1024

__device__ __forceinline__ unsigned short f2bf(float f) {
  unsigned u = __float_as_uint(f);
  u = (u + 0x7FFFu + ((u >> 16) & 1u)) >> 16;  // RNE
  return (unsigned short)u;
}

__device__ __forceinline__ void async_copy16(void* lds, const void* g) {
  __builtin_amdgcn_global_load_lds(
      (const __attribute__((address_space(1))) unsigned*)g,
      (__attribute__((address_space(3))) unsigned*)lds, 16, 0, 0);
}

// ---- prepass: A fp32 -> bf16 (streaming, memory-bound, ~83 us = BW floor) ----
__global__ void convert_a_kernel(const float* __restrict__ A,
                                 unsigned short* __restrict__ Abf, long n8) {
  long i = (long)blockIdx.x * blockDim.x + threadIdx.x;
  long stride = (long)gridDim.x * blockDim.x;
  for (; i < n8; i += stride) {
    const float* p = A + i * 8;
    float4 f0 = *(const float4*)p;
    float4 f1 = *(const float4*)(p + 4);
    int4 pk;
    pk.x = f2bf(f0.x) | ((unsigned)f2bf(f0.y) << 16);
    pk.y = f2bf(f0.z) | ((unsigned)f2bf(f0.w) << 16);
    pk.z = f2bf(f1.x) | ((unsigned)f2bf(f1.y) << 16);
    pk.w = f2bf(f1.z) | ((unsigned)f2bf(f1.w) << 16);
    *(int4*)(Abf + i * 8) = pk;
  }
}

// W1 [d][h] fp32 -> W1T [h][d] bf16
__global__ void transpose_w1_kernel(const float* __restrict__ W1,
                                    unsigned short* __restrict__ W1T) {
  __shared__ float tile[32][33];
  int bx = blockIdx.x, by = blockIdx.y;
  int tx = threadIdx.x, ty = threadIdx.y;
#pragma unroll
  for (int i = 0; i < 32; i += 8)
    tile[ty + i][tx] = W1[(size_t)(by * 32 + ty + i) * HID + bx * 32 + tx];
  __syncthreads();
#pragma unroll
  for (int i = 0; i < 32; i += 8)
    W1T[(size_t)(bx * 32 + ty + i) * DDIM + by * 32 + tx] = f2bf(tile[tx][ty + i]);
}

__global__ void init_out_kernel(float* __restrict__ out, const float* __restrict__ b2, int n) {
  int i = blockIdx.x * blockDim.x + threadIdx.x;
  if (i < n) out[i] = b2[0];
}

// ---- main: m97-structure GEMM, both tiles bf16 via global_load_lds ----
// 128x128 tile, BK=64, 4 waves (2x2), 2-barrier loop. Measured 211-213 us /
// ~882 TF / MfmaUtil 40% / 0 bank conflicts — at the documented ceiling for
// this structure (m97/m103: 874-912 TF). Deep-pipeline variants (rounds
// 6-9, 11: coarse/2-phase/4-phase counted-vmcnt, 560-660 TF) all measured
// worse: at 1 block/CU the barrier convoy forfeits the cross-block wave
// overlap (m114) that this 2-block/CU structure exploits. LDS: linear DMA
// dest + inverse-swizzled source (involution: chunk ^= row&7 on 16B chunks
// of 128B rows), same XOR on read.
__launch_bounds__(256, 2)
__global__ void fused_mlp_kernel(const unsigned short* __restrict__ Abf,
                                 const unsigned short* __restrict__ W1T,
                                 const float* __restrict__ b1,
                                 const float* __restrict__ W2,
                                 float* __restrict__ out) {
  __shared__ __align__(16) unsigned short As[128 * 64];  // 16 KB
  __shared__ __align__(16) unsigned short Bs[128 * 64];  // 16 KB

  int bid = blockIdx.x;
  // bijective XCD swizzle: 5600 = 8 XCDs * 700
  int w = (bid & 7) * 700 + (bid >> 3);
  int blk_m = w >> 3;  // residue r: 0..699
  int blk_n = w & 7;   // 0..7
  int m0 = blk_m * 128;
  int n0 = blk_n * 128;

  int t = threadIdx.x;
  int lane = t & 63;
  int wid = t >> 6;
  int wm = wid >> 1, wn = wid & 1;       // 2x2 waves, 64x64 each
  int lrow = lane & 15, lk = lane >> 4;  // fragment decomposition

  floatx4 acc[4][4];
#pragma unroll
  for (int i = 0; i < 4; ++i)
#pragma unroll
    for (int j = 0; j < 4; ++j) acc[i][j] = (floatx4)(0.f);

  for (int kt = 0; kt < 16; ++kt) {
    int k0 = kt * 64;
    // ---- stage: 4 DMA copies per matrix per thread, no reg round-trip ----
#pragma unroll
    for (int i = 0; i < 4; ++i) {
      int base_chunk = i * 256 + wid * 64;  // wave-uniform LDS base (16B chunks)
      int c = base_chunk + lane;            // this lane's chunk
      int row = c >> 3, slot = c & 7;
      int sc = slot ^ (row & 7);            // inverse-swizzled source chunk
      async_copy16(&As[base_chunk * 8], Abf + (size_t)(m0 + row) * DDIM + k0 + sc * 8);
      async_copy16(&Bs[base_chunk * 8], W1T + (size_t)(n0 + row) * DDIM + k0 + sc * 8);
    }
    __syncthreads();  // compiler emits vmcnt(0) drain before s_barrier

    // ---- compute: 2 k-slices of 32, 16 MFMA each ----
#pragma unroll
    for (int ks = 0; ks < 2; ++ks) {
      short8 af[4], bf[4];
#pragma unroll
      for (int f = 0; f < 4; ++f) {
        int arow = wm * 64 + f * 16 + lrow;
        int ac = (ks * 4 + lk) ^ (arow & 7);
        af[f] = *(const short8*)(&As[arow * 64 + ac * 8]);
        int brow = wn * 64 + f * 16 + lrow;
        int bc = (ks * 4 + lk) ^ (brow & 7);
        bf[f] = *(const short8*)(&Bs[brow * 64 + bc * 8]);
      }
#pragma unroll
      for (int fm = 0; fm < 4; ++fm)
#pragma unroll
        for (int fn = 0; fn < 4; ++fn)
          acc[fm][fn] = __builtin_amdgcn_mfma_f32_16x16x32_bf16(af[fm], bf[fn], acc[fm][fn], 0, 0, 0);
    }
    __syncthreads();  // protect LDS before next stage
  }

  // ---- epilogue: +b1, relu, dot W2, shfl-reduce 16 cols, atomicAdd ----
  float w2v[4], b1v[4];
#pragma unroll
  for (int fn = 0; fn < 4; ++fn) {
    int col = n0 + wn * 64 + fn * 16 + lrow;
    w2v[fn] = W2[col];
    b1v[fn] = b1[col];
  }
#pragma unroll
  for (int fm = 0; fm < 4; ++fm) {
#pragma unroll
    for (int j = 0; j < 4; ++j) {
      float p = 0.f;
#pragma unroll
      for (int fn = 0; fn < 4; ++fn) {
        float h = acc[fm][fn][j] + b1v[fn];
        h = fmaxf(h, 0.f);
        p += h * w2v[fn];
      }
      p += __shfl_xor(p, 1);
      p += __shfl_xor(p, 2);
      p += __shfl_xor(p, 4);
      p += __shfl_xor(p, 8);
      if ((lane & 15) == 0) {
        int row = wm * 64 + fm * 16 + (lk << 2) + j;  // local row = batch b
        atomicAdd(&out[row * NRES + blk_m], p);       // out[b*700 + r]
      }
    }
  }
}

// ---- fallback (round-2 kernel, proven 435 us): used if ws_size too small ----
__launch_bounds__(256, 2)
__global__ void fused_mlp_fallback(const float* __restrict__ A,
                                   const unsigned short* __restrict__ W1T,
                                   const float* __restrict__ b1,
                                   const float* __restrict__ W2,
                                   float* __restrict__ out) {
  __shared__ unsigned short As[128 * 64];
  __shared__ unsigned short Bs[128 * 64];
  int bid = blockIdx.x;
  int w = (bid & 7) * 700 + (bid >> 3);
  int blk_m = w >> 3, blk_n = w & 7;
  int m0 = blk_m * 128, n0 = blk_n * 128;
  int t = threadIdx.x, lane = t & 63, wid = t >> 6;
  int wm = wid >> 1, wn = wid & 1;
  int lrow = lane & 15, lk = lane >> 4;
  floatx4 acc[4][4];
#pragma unroll
  for (int i = 0; i < 4; ++i)
#pragma unroll
    for (int j = 0; j < 4; ++j) acc[i][j] = (floatx4)(0.f);
  for (int kt = 0; kt < 16; ++kt) {
    int k0 = kt * 64;
#pragma unroll
    for (int i = 0; i < 4; ++i) {
      int c = i * 256 + t;
      int row = c >> 3, c8 = c & 7;
      int dst = row * 64 + ((c8 ^ (row & 7)) * 8);
      const float* gp = A + (size_t)(m0 + row) * DDIM + k0 + c8 * 8;
      float4 f0 = *(const float4*)gp;
      float4 f1 = *(const float4*)(gp + 4);
      int4 pk;
      pk.x = f2bf(f0.x) | ((unsigned)f2bf(f0.y) << 16);
      pk.y = f2bf(f0.z) | ((unsigned)f2bf(f0.w) << 16);
      pk.z = f2bf(f1.x) | ((unsigned)f2bf(f1.y) << 16);
      pk.w = f2bf(f1.z) | ((unsigned)f2bf(f1.w) << 16);
      *(int4*)(&As[dst]) = pk;
      const unsigned short* gb = W1T + (size_t)(n0 + row) * DDIM + k0 + c8 * 8;
      *(int4*)(&Bs[dst]) = *(const int4*)gb;
    }
    __syncthreads();
#pragma unroll
    for (int ks = 0; ks < 2; ++ks) {
      short8 af[4], bf[4];
#pragma unroll
      for (int f = 0; f < 4; ++f) {
        int arow = wm * 64 + f * 16 + lrow;
        int ac = (ks * 4 + lk) ^ (arow & 7);
        af[f] = *(const short8*)(&As[arow * 64 + ac * 8]);
        int brow = wn * 64 + f * 16 + lrow;
        int bc = (ks * 4 + lk) ^ (brow & 7);
        bf[f] = *(const short8*)(&Bs[brow * 64 + bc * 8]);
      }
#pragma unroll
      for (int fm = 0; fm < 4; ++fm)
#pragma unroll
        for (int fn = 0; fn < 4; ++fn)
          acc[fm][fn] = __builtin_amdgcn_mfma_f32_16x16x32_bf16(af[fm], bf[fn], acc[fm][fn], 0, 0, 0);
    }
    __syncthreads();
  }
  float w2v[4], b1v[4];
#pragma unroll
  for (int fn = 0; fn < 4; ++fn) {
    int col = n0 + wn * 64 + fn * 16 + lrow;
    w2v[fn] = W2[col];
    b1v[fn] = b1[col];
  }
#pragma unroll
  for (int fm = 0; fm < 4; ++fm) {
#pragma unroll
    for (int j = 0; j < 4; ++j) {
      float p = 0.f;
#pragma unroll
      for (int fn = 0; fn < 4; ++fn) {
        float h = acc[fm][fn][j] + b1v[fn];
        h = fmaxf(h, 0.f);
        p += h * w2v[fn];
      }
      p += __shfl_xor(p, 1);
      p += __shfl_xor(p, 2);
      p += __shfl_xor(p, 4);
      p += __shfl_xor(p, 8);
      if ((lane & 15) == 0) {
        int row = wm * 64 + fm * 16 + (lk << 2) + j;
        atomicAdd(&out[row * NRES + blk_m], p);
      }
    }
  }
}

extern "C" void kernel_launch(void* const* d_in, const int* in_sizes, int n_in,
                              void* d_out, int out_size, void* d_ws, size_t ws_size,
                              hipStream_t stream) {
  const float* s_s = (const float*)d_in[0];  // [700,128,1024] fp32
  const float* W1 = (const float*)d_in[1];   // [1024,1024]
  const float* b1 = (const float*)d_in[2];   // [1024]
  const float* W2 = (const float*)d_in[3];   // [1024,1]
  const float* b2 = (const float*)d_in[4];   // [1]
  float* out = (float*)d_out;                // [128,700,1] fp32

  unsigned short* W1T = (unsigned short*)d_ws;  // 2 MB bf16
  const size_t w1t_bytes = (size_t)HID * DDIM * 2;
  const size_t abf_bytes = (size_t)NRES * 128 * DDIM * 2;  // 183.5 MB

  dim3 tb(32, 8);
  dim3 tg(HID / 32, DDIM / 32);
  transpose_w1_kernel<<<tg, tb, 0, stream>>>(W1, W1T);

  init_out_kernel<<<(out_size + 255) / 256, 256, 0, stream>>>(out, b2, out_size);

  if (ws_size >= w1t_bytes + abf_bytes) {
    unsigned short* Abf = (unsigned short*)((char*)d_ws + w1t_bytes);
    long n8 = (long)NRES * 128 * DDIM / 8;
    convert_a_kernel<<<2048, 256, 0, stream>>>(s_s, Abf, n8);
    fused_mlp_kernel<<<NRES * 8, 256, 0, stream>>>(Abf, W1T, b1, W2, out);
  } else {
    fused_mlp_fallback<<<NRES * 8, 256, 0, stream>>>(s_s, W1T, b1, W2, out);
  }
}